// Round 5
// baseline (248.570 us; speedup 1.0000x reference)
//
#include <hip/hip_runtime.h>

// Planar NF v5: scalar-path tables.
//  nf_gen (1 block, proven): Wt=[d][32], uhat[k][256], G[k][32], c[32] -> ws.
//  nf_fused (512 blocks, 128 thr = 2 waves, ROWS=128):
//   Wave w owns k-block [16w,16w+16) in phase 1 and col-block in phase 3; all
//   w/uhat/G/c/b reads are wave-uniform (readfirstlane) -> s_load (SGPR operands,
//   no LDS/VMEM-vector cost). Lane owns rows (2l, 2l+1): X via LDS ds_read_b64,
//   T via ds_read_b64 — bandwidth-minimal. LDS = Xs/T (16K, aliased) + P (16K).

#define B_ 65536
#define D_ 256
#define ROWS 128
#define GRID (B_ / ROWS)
#define NTHR 128

#define WS_WT 0      // Wt [d][32]
#define WS_UH 8192   // uhat [k][256]
#define WS_G  16384  // G [k][32]
#define WS_C  17408  // c[32]

#define XS 0         // Xs chunk [32 c][128 r] swizzled; aliased as T [32 k][128 r]
#define TS 0
#define PS 4096      // P [32 k][128 r]

__global__ __launch_bounds__(256) void nf_gen(const float* __restrict__ u_in,
                                              const float* __restrict__ w_in,
                                              float* __restrict__ ws) {
  __shared__ float wTg[8192];  // [d][k]
  __shared__ float ug[8192];   // [j][d]
  __shared__ float wu_s[32], ww_s[32], coefs_s[32];
  const int t = threadIdx.x;
  {
    const int k = t & 31, d0 = (t >> 5) * 32;
    const float4* wp = (const float4*)(w_in + k * 256 + d0);
#pragma unroll
    for (int q = 0; q < 8; ++q) {
      float4 v = wp[q];
      wTg[(d0 + q * 4 + 0) * 32 + k] = v.x;
      wTg[(d0 + q * 4 + 1) * 32 + k] = v.y;
      wTg[(d0 + q * 4 + 2) * 32 + k] = v.z;
      wTg[(d0 + q * 4 + 3) * 32 + k] = v.w;
    }
#pragma unroll
    for (int q = 0; q < 8; ++q)
      ((float4*)ug)[t + 256 * q] = ((const float4*)u_in)[t + 256 * q];
  }
  __syncthreads();
  const int k = t & 31, jg = t >> 5;  // row k, cols jg*4..+4
  float m1[4] = {0.f, 0.f, 0.f, 0.f}, m2[4] = {0.f, 0.f, 0.f, 0.f};
#pragma unroll 4
  for (int dc = 0; dc < 64; ++dc) {
    float wk[4];
    float4 wj[4], uj[4];
#pragma unroll
    for (int i = 0; i < 4; ++i) wk[i] = wTg[(dc * 4 + i) * 32 + k];
#pragma unroll
    for (int i = 0; i < 4; ++i) wj[i] = *(const float4*)&wTg[(dc * 4 + i) * 32 + jg * 4];
#pragma unroll
    for (int i = 0; i < 4; ++i) uj[i] = *(const float4*)&ug[(jg * 4 + i) * 256 + dc * 4];
#pragma unroll
    for (int i = 0; i < 4; ++i) {
      m1[i] = fmaf(uj[i].x, wk[0], m1[i]);
      m1[i] = fmaf(uj[i].y, wk[1], m1[i]);
      m1[i] = fmaf(uj[i].z, wk[2], m1[i]);
      m1[i] = fmaf(uj[i].w, wk[3], m1[i]);
    }
    const float* w0 = (const float*)&wj[0];
    const float* w1 = (const float*)&wj[1];
    const float* w2 = (const float*)&wj[2];
    const float* w3 = (const float*)&wj[3];
#pragma unroll
    for (int i = 0; i < 4; ++i) {
      m2[i] = fmaf(w0[i], wk[0], m2[i]);
      m2[i] = fmaf(w1[i], wk[1], m2[i]);
      m2[i] = fmaf(w2[i], wk[2], m2[i]);
      m2[i] = fmaf(w3[i], wk[3], m2[i]);
    }
  }
  if ((k >> 2) == jg) {  // holds diagonal j==k
    wu_s[k] = m1[k & 3];
    ww_s[k] = m2[k & 3];
  }
  __syncthreads();
  if (t < 32) {
    float wu = wu_s[t], ww = ww_s[t];
    float sp = fmaxf(wu, 0.f) + log1pf(__expf(-fabsf(wu)));
    coefs_s[t] = (sp - 1.f - wu) / ww;
    ws[WS_C + t] = sp - 1.f;  // c_k = w_k.uhat_k
  }
  __syncthreads();
#pragma unroll
  for (int i = 0; i < 4; ++i)
    ws[WS_G + k * 32 + jg * 4 + i] = fmaf(coefs_s[jg * 4 + i], m2[i], m1[i]);
  {
    const int k2 = t >> 3, d0 = (t & 7) * 32;
    const float ck = coefs_s[k2];
    const float4* up = (const float4*)(u_in + k2 * 256 + d0);
    const float4* wp2 = (const float4*)(w_in + k2 * 256 + d0);
    float4* od = (float4*)(ws + WS_UH + k2 * 256 + d0);
#pragma unroll
    for (int q = 0; q < 8; ++q) {
      float4 uv = up[q], wv = wp2[q];
      uv.x = fmaf(ck, wv.x, uv.x);
      uv.y = fmaf(ck, wv.y, uv.y);
      uv.z = fmaf(ck, wv.z, uv.z);
      uv.w = fmaf(ck, wv.w, uv.w);
      od[q] = uv;
    }
  }
#pragma unroll
  for (int q = 0; q < 8; ++q)
    ((float4*)(ws + WS_WT))[t + 256 * q] = ((const float4*)wTg)[t + 256 * q];
}

__global__ __launch_bounds__(NTHR, 2) void nf_fused(const float* __restrict__ X,
                                                    const float* __restrict__ b_in,
                                                    const float* __restrict__ ws,
                                                    float* __restrict__ out) {
  __shared__ float lds[8192];  // 32 KB

  const int t = threadIdx.x;
  const int lane = t & 63;
  const int wvu = __builtin_amdgcn_readfirstlane(t >> 6);  // wave id 0/1 (uniform)
  const int row0 = blockIdx.x * ROWS;
  const int r2 = 2 * lane;       // this lane's rows: r2, r2+1
  const int srow = t >> 2;       // staging row 0..31 (+32*rp)
  const int scol = (t & 3) * 8;  // staging col octet (chunk-local)

  // ---------------- phase 1: p = X . w ----------------
  float4 pf[8];
  auto load_stage = [&](int s) {
#pragma unroll
    for (int rp = 0; rp < 4; ++rp) {
      const float* src = X + (size_t)(row0 + rp * 32 + srow) * 256 + s * 32 + scol;
      pf[rp * 2 + 0] = ((const float4*)src)[0];
      pf[rp * 2 + 1] = ((const float4*)src)[1];
    }
  };
  auto store_stage = [&]() {
#pragma unroll
    for (int rp = 0; rp < 4; ++rp) {
      const int row = rp * 32 + srow;
      const float f[8] = {pf[rp * 2].x,     pf[rp * 2].y,     pf[rp * 2].z,
                          pf[rp * 2].w,     pf[rp * 2 + 1].x, pf[rp * 2 + 1].y,
                          pf[rp * 2 + 1].z, pf[rp * 2 + 1].w};
#pragma unroll
      for (int i = 0; i < 8; ++i) {
        const int c = scol + i;
        lds[XS + c * 128 + ((row + 6 * c) & 127)] = f[i];  // 2-way max: free
      }
    }
  };

  float p0[16], p1[16];
#pragma unroll
  for (int i = 0; i < 16; ++i) { p0[i] = 0.f; p1[i] = 0.f; }

  load_stage(0);
  const float* wtab = ws + WS_WT + wvu * 16;  // wave's k-block, uniform -> s_load
  for (int s = 0; s < 8; ++s) {
    store_stage();
    __syncthreads();
    if (s < 7) load_stage(s + 1);
#pragma unroll 4
    for (int dl = 0; dl < 32; ++dl) {
      const int d = s * 32 + dl;
      float2 xv = *(const float2*)&lds[XS + dl * 128 + ((r2 + 6 * dl) & 127)];
      const float* wk = wtab + d * 32;  // 16 consecutive floats, wave-uniform
#pragma unroll
      for (int i = 0; i < 16; ++i) {
        p0[i] = fmaf(xv.x, wk[i], p0[i]);
        p1[i] = fmaf(xv.y, wk[i], p1[i]);
      }
    }
    __syncthreads();
  }

  // ---------------- P dump [k][r] ----------------
  {
    const int kb = wvu * 16;
#pragma unroll
    for (int i = 0; i < 16; ++i)
      *(float2*)&lds[PS + (kb + i) * 128 + r2] = make_float2(p0[i], p1[i]);
  }
  __syncthreads();

  // ---------------- recurrence: one row per thread (all 128) ----------------
  {
    float pfull[32];
#pragma unroll
    for (int j = 0; j < 32; ++j) pfull[j] = lds[PS + j * 128 + t] + b_in[j];
    float tvv[32];
#pragma unroll
    for (int kk = 0; kk < 32; ++kk) {
      float la = pfull[kk], lb = 0.f;
      const float* gp = ws + WS_G + kk * 32;  // uniform -> s_load
#pragma unroll
      for (int j = 0; j + 1 < kk; j += 2) {
        la = fmaf(tvv[j], gp[j], la);
        lb = fmaf(tvv[j + 1], gp[j + 1], lb);
      }
      if (kk & 1) la = fmaf(tvv[kk - 1], gp[kk - 1], la);
      float lin = la + lb;
      float e = __expf(2.f * lin);
      float tk = 1.f - 2.f / (e + 1.f);
      tvv[kk] = tk;
      lds[TS + kk * 128 + t] = tk;  // T [k][r] (Xs region, now dead)
      float val = fabsf(fmaf(1.f - tk * tk, ws[WS_C + kk], 1.f)) + 1e-8f;
      out[(size_t)B_ * D_ + (size_t)kk * B_ + row0 + t] = __logf(val);
    }
  }
  __syncthreads();

  // ---------------- phase 3: z = X + T . uhat ----------------
  const float* uws = ws + WS_UH;
  for (int ps = 0; ps < 4; ++ps) {
    const int c0 = ps * 64 + wvu * 32;  // wave-uniform col block
    float a0[32], a1[32];
    {
      const float* x0 = X + (size_t)(row0 + r2) * 256 + c0;
      const float* x1 = X + (size_t)(row0 + r2 + 1) * 256 + c0;
#pragma unroll
      for (int q = 0; q < 8; ++q) {
        float4 v0 = ((const float4*)x0)[q];
        float4 v1 = ((const float4*)x1)[q];
        a0[q * 4 + 0] = v0.x; a0[q * 4 + 1] = v0.y;
        a0[q * 4 + 2] = v0.z; a0[q * 4 + 3] = v0.w;
        a1[q * 4 + 0] = v1.x; a1[q * 4 + 1] = v1.y;
        a1[q * 4 + 2] = v1.z; a1[q * 4 + 3] = v1.w;
      }
    }
#pragma unroll 2
    for (int kk = 0; kk < 32; ++kk) {
      float2 tv = *(const float2*)&lds[TS + kk * 128 + r2];
      const float* uk = uws + kk * 256 + c0;  // 32 floats, wave-uniform -> s_load
#pragma unroll
      for (int c = 0; c < 32; ++c) {
        a0[c] = fmaf(tv.x, uk[c], a0[c]);
        a1[c] = fmaf(tv.y, uk[c], a1[c]);
      }
    }
    {
      float* o0 = out + (size_t)(row0 + r2) * 256 + c0;
      float* o1 = out + (size_t)(row0 + r2 + 1) * 256 + c0;
#pragma unroll
      for (int q = 0; q < 8; ++q) {
        ((float4*)o0)[q] = make_float4(a0[q * 4], a0[q * 4 + 1], a0[q * 4 + 2], a0[q * 4 + 3]);
        ((float4*)o1)[q] = make_float4(a1[q * 4], a1[q * 4 + 1], a1[q * 4 + 2], a1[q * 4 + 3]);
      }
    }
  }
}

extern "C" void kernel_launch(void* const* d_in, const int* in_sizes, int n_in,
                              void* d_out, int out_size, void* d_ws, size_t ws_size,
                              hipStream_t stream) {
  const float* X = (const float*)d_in[0];
  // d_in[1] = h : unused by the math
  const float* u = (const float*)d_in[2];
  const float* w = (const float*)d_in[3];
  const float* b = (const float*)d_in[4];
  float* out = (float*)d_out;
  float* ws = (float*)d_ws;

  nf_gen<<<1, 256, 0, stream>>>(u, w, ws);
  nf_fused<<<GRID, NTHR, 0, stream>>>(X, b, ws, out);
}

// Round 6
// 211.310 us; speedup vs baseline: 1.1763x; 1.1763x over previous
//
#include <hip/hip_runtime.h>

// Planar NF v6: MFMA (bf16 hi/lo 3-pass) for both GEMM phases.
//  nf_gen (1 block): G[k][32], c[32] (fp32), W hi/lo bf16 [32][264],
//                    Uhat^T hi/lo bf16 [256][40]  -> workspace.
//  nf_fused (512 blocks, 256 thr = 4 waves, ROWS=128, LDS 75264B -> 2 blk/CU):
//   phase1: P = X.W^T via mfma_f32_16x16x32_bf16, 8 d-chunks staged as bf16 hi/lo
//   recurrence: unchanged scalar chain (proven), T -> LDS as bf16 hi/lo [r][40]
//   phase3: Z = X + T.Uhat via MFMA, X in through the C operand, U from LDS.
// All LDS strides odd multiples of 16B (<=2-way conflicts). Frag layouts per
// m97-verified pattern: A row=lane&15,k=(lane>>4)*8+e; B col=lane&15,same k;
// C/D col=lane&15,row=(lane>>4)*4+reg.

typedef __attribute__((ext_vector_type(8))) short short8;
typedef __attribute__((ext_vector_type(4))) float f32x4;

#define B_ 65536
#define D_ 256
#define ROWS 128
#define GRID (B_ / ROWS)

// workspace byte offsets
#define WSB_WH 0       // W hi bf16 [32][264]
#define WSB_WL 16896   // W lo
#define WSB_UTH 33792  // Uhat^T hi bf16 [256][40]
#define WSB_UTL 54272  // Uhat^T lo
#define WSB_G 74752    // G fp32 [32][32]
#define WSB_C 78848    // c fp32 [32]

// lds float offsets
#define OFF_P 8448   // P fp32 [32][129]
#define OFF_G 17696  // G fp32 [32][33]
#define OFF_C 18752
#define OFF_B 18784
#define LDSF 18816
// lds half offsets
#define WH_H 0      // W hi [32][264] (phase 1) / U hi [256][40] (phase 3 overlay)
#define WL_H 8448   // W lo
#define UH_H 0
#define UL_H 10240
#define XH_H 25152  // X-chunk / T hi [128][40]
#define XL_H 30272  // lo

__device__ __forceinline__ void bfsplit(float x, unsigned short& h, unsigned short& l) {
  unsigned xb = __float_as_uint(x) & 0xffff0000u;
  h = (unsigned short)(xb >> 16);
  float r = x - __uint_as_float(xb);
  l = (unsigned short)(__float_as_uint(r) >> 16);
}

__global__ __launch_bounds__(256) void nf_gen(const float* __restrict__ u_in,
                                              const float* __restrict__ w_in,
                                              float* __restrict__ ws) {
  __shared__ float wTg[8192];  // [d][k]
  __shared__ float ug[8192];   // [j][d]
  __shared__ float wu_s[32], ww_s[32], coefs_s[32];
  const int t = threadIdx.x;
  {
    const int k = t & 31, d0 = (t >> 5) * 32;
    const float4* wp = (const float4*)(w_in + k * 256 + d0);
#pragma unroll
    for (int q = 0; q < 8; ++q) {
      float4 v = wp[q];
      wTg[(d0 + q * 4 + 0) * 32 + k] = v.x;
      wTg[(d0 + q * 4 + 1) * 32 + k] = v.y;
      wTg[(d0 + q * 4 + 2) * 32 + k] = v.z;
      wTg[(d0 + q * 4 + 3) * 32 + k] = v.w;
    }
#pragma unroll
    for (int q = 0; q < 8; ++q)
      ((float4*)ug)[t + 256 * q] = ((const float4*)u_in)[t + 256 * q];
  }
  __syncthreads();
  const int k = t & 31, jg = t >> 5;  // row k, cols jg*4..+4
  float m1[4] = {0.f, 0.f, 0.f, 0.f}, m2[4] = {0.f, 0.f, 0.f, 0.f};
#pragma unroll 4
  for (int dc = 0; dc < 64; ++dc) {
    float wk[4];
    float4 wj[4], uj[4];
#pragma unroll
    for (int i = 0; i < 4; ++i) wk[i] = wTg[(dc * 4 + i) * 32 + k];
#pragma unroll
    for (int i = 0; i < 4; ++i) wj[i] = *(const float4*)&wTg[(dc * 4 + i) * 32 + jg * 4];
#pragma unroll
    for (int i = 0; i < 4; ++i) uj[i] = *(const float4*)&ug[(jg * 4 + i) * 256 + dc * 4];
#pragma unroll
    for (int i = 0; i < 4; ++i) {
      m1[i] = fmaf(uj[i].x, wk[0], m1[i]);
      m1[i] = fmaf(uj[i].y, wk[1], m1[i]);
      m1[i] = fmaf(uj[i].z, wk[2], m1[i]);
      m1[i] = fmaf(uj[i].w, wk[3], m1[i]);
    }
    const float* w0 = (const float*)&wj[0];
    const float* w1 = (const float*)&wj[1];
    const float* w2 = (const float*)&wj[2];
    const float* w3 = (const float*)&wj[3];
#pragma unroll
    for (int i = 0; i < 4; ++i) {
      m2[i] = fmaf(w0[i], wk[0], m2[i]);
      m2[i] = fmaf(w1[i], wk[1], m2[i]);
      m2[i] = fmaf(w2[i], wk[2], m2[i]);
      m2[i] = fmaf(w3[i], wk[3], m2[i]);
    }
  }
  if ((k >> 2) == jg) {  // holds diagonal j==k
    wu_s[k] = m1[k & 3];
    ww_s[k] = m2[k & 3];
  }
  __syncthreads();
  if (t < 32) {
    float wu = wu_s[t], ww = ww_s[t];
    float sp = fmaxf(wu, 0.f) + log1pf(__expf(-fabsf(wu)));
    coefs_s[t] = (sp - 1.f - wu) / ww;
    ((float*)((char*)ws + WSB_C))[t] = sp - 1.f;  // c_k
  }
  __syncthreads();
  {
    float* gws = (float*)((char*)ws + WSB_G);
#pragma unroll
    for (int i = 0; i < 4; ++i)
      gws[k * 32 + jg * 4 + i] = fmaf(coefs_s[jg * 4 + i], m2[i], m1[i]);
  }
  // bf16 hi/lo outputs: W [32][264], Uhat^T [256][40]
  {
    const int k2 = t >> 3, d0 = (t & 7) * 32;
    const float ck = coefs_s[k2];
    unsigned short* whp = (unsigned short*)((char*)ws + WSB_WH);
    unsigned short* wlp = (unsigned short*)((char*)ws + WSB_WL);
    unsigned short* uthp = (unsigned short*)((char*)ws + WSB_UTH);
    unsigned short* utlp = (unsigned short*)((char*)ws + WSB_UTL);
    const float4* wp2 = (const float4*)(w_in + k2 * 256 + d0);
    const float4* up2 = (const float4*)(u_in + k2 * 256 + d0);
#pragma unroll
    for (int q = 0; q < 8; ++q) {
      float4 wv = wp2[q], uv = up2[q];
      const float wf[4] = {wv.x, wv.y, wv.z, wv.w};
      const float uf[4] = {uv.x, uv.y, uv.z, uv.w};
#pragma unroll
      for (int i = 0; i < 4; ++i) {
        unsigned short hh, ll;
        bfsplit(wf[i], hh, ll);
        whp[k2 * 264 + d0 + q * 4 + i] = hh;
        wlp[k2 * 264 + d0 + q * 4 + i] = ll;
        float uhv = fmaf(ck, wf[i], uf[i]);
        bfsplit(uhv, hh, ll);
        uthp[(d0 + q * 4 + i) * 40 + k2] = hh;
        utlp[(d0 + q * 4 + i) * 40 + k2] = ll;
      }
    }
  }
}

__global__ __launch_bounds__(256) void nf_fused(const float* __restrict__ X,
                                                const float* __restrict__ b_in,
                                                const float* __restrict__ ws,
                                                float* __restrict__ out) {
  __shared__ __align__(16) float lds[LDSF];
  unsigned short* ldsH = (unsigned short*)lds;

  const int t = threadIdx.x;
  const int lane = t & 63;
  const int wv = t >> 6;
  const int ln15 = lane & 15;
  const int g = lane >> 4;  // 0..3
  const int g8 = g * 8, g4 = g * 4;
  const int row0 = blockIdx.x * ROWS;

  // stage W hi/lo bf16 into LDS (coalesced uint4 copy: 33792 B = 2112 uint4)
  {
    const uint4* wsrc = (const uint4*)((const char*)ws + WSB_WH);
    uint4* wdst = (uint4*)lds;
#pragma unroll
    for (int i = 0; i < 8; ++i) wdst[t + 256 * i] = wsrc[t + 256 * i];
    if (t < 64) wdst[2048 + t] = wsrc[2048 + t];
  }
  // stage G/c/b
#pragma unroll
  for (int i = 0; i < 4; ++i) {
    const int e = t * 4 + i;
    lds[OFF_G + (e >> 5) * 33 + (e & 31)] = ((const float*)((const char*)ws + WSB_G))[e];
  }
  if (t < 32) {
    lds[OFF_C + t] = ((const float*)((const char*)ws + WSB_C))[t];
    lds[OFF_B + t] = b_in[t];
  }

  // phase-1 X chunk staging (row srow, 16 d starting at sdh)
  const int srow = t >> 1;
  const int sdh = (t & 1) * 16;
  float4 xr[4];
  auto load_stage = [&](int cc) {
    const float4* src = (const float4*)(X + (size_t)(row0 + srow) * 256 + cc * 32 + sdh);
#pragma unroll
    for (int j = 0; j < 4; ++j) xr[j] = src[j];
  };
  auto store_stage = [&]() {
    float xf[16];
#pragma unroll
    for (int j = 0; j < 4; ++j) {
      xf[j * 4 + 0] = xr[j].x; xf[j * 4 + 1] = xr[j].y;
      xf[j * 4 + 2] = xr[j].z; xf[j * 4 + 3] = xr[j].w;
    }
    short8 h0, h1, l0, l1;
#pragma unroll
    for (int e = 0; e < 8; ++e) {
      unsigned short hh, ll;
      bfsplit(xf[e], hh, ll);
      h0[e] = (short)hh; l0[e] = (short)ll;
      bfsplit(xf[8 + e], hh, ll);
      h1[e] = (short)hh; l1[e] = (short)ll;
    }
    *(short8*)&ldsH[XH_H + srow * 40 + sdh] = h0;
    *(short8*)&ldsH[XH_H + srow * 40 + sdh + 8] = h1;
    *(short8*)&ldsH[XL_H + srow * 40 + sdh] = l0;
    *(short8*)&ldsH[XL_H + srow * 40 + sdh + 8] = l1;
  };

  // ---------------- phase 1: P = X . W^T (MFMA) ----------------
  f32x4 acc[2][2];
#pragma unroll
  for (int m = 0; m < 2; ++m)
#pragma unroll
    for (int n = 0; n < 2; ++n) acc[m][n] = (f32x4){0.f, 0.f, 0.f, 0.f};

  load_stage(0);
  for (int cc = 0; cc < 8; ++cc) {
    store_stage();
    __syncthreads();
    if (cc < 7) load_stage(cc + 1);
    short8 ah[2], al[2], bh[2], bl[2];
#pragma unroll
    for (int m = 0; m < 2; ++m) {
      const int hidx = XH_H + ((wv * 2 + m) * 16 + ln15) * 40 + g8;
      ah[m] = *(const short8*)&ldsH[hidx];
      al[m] = *(const short8*)&ldsH[hidx + (XL_H - XH_H)];
    }
#pragma unroll
    for (int n = 0; n < 2; ++n) {
      const int widx = (n * 16 + ln15) * 264 + cc * 32 + g8;
      bh[n] = *(const short8*)&ldsH[WH_H + widx];
      bl[n] = *(const short8*)&ldsH[WL_H + widx];
    }
#pragma unroll
    for (int m = 0; m < 2; ++m)
#pragma unroll
      for (int n = 0; n < 2; ++n) {
        acc[m][n] = __builtin_amdgcn_mfma_f32_16x16x32_bf16(ah[m], bh[n], acc[m][n], 0, 0, 0);
        acc[m][n] = __builtin_amdgcn_mfma_f32_16x16x32_bf16(ah[m], bl[n], acc[m][n], 0, 0, 0);
        acc[m][n] = __builtin_amdgcn_mfma_f32_16x16x32_bf16(al[m], bh[n], acc[m][n], 0, 0, 0);
      }
    __syncthreads();
  }

  // ---------------- P dump [k][129] ----------------
#pragma unroll
  for (int m = 0; m < 2; ++m)
#pragma unroll
    for (int n = 0; n < 2; ++n)
#pragma unroll
      for (int q = 0; q < 4; ++q)
        lds[OFF_P + (n * 16 + ln15) * 129 + ((wv * 2 + m) * 16 + g4 + q)] = acc[m][n][q];
  __syncthreads();

  // ---------------- recurrence: one row per thread ----------------
  if (t < 128) {
    float pfull[32];
#pragma unroll
    for (int j = 0; j < 32; ++j) pfull[j] = lds[OFF_P + j * 129 + t] + lds[OFF_B + j];
    float tvv[32];
#pragma unroll
    for (int kk = 0; kk < 32; ++kk) {
      float la = pfull[kk], lb2 = 0.f;
      const float* gp = &lds[OFF_G + kk * 33];
#pragma unroll
      for (int j = 0; j + 1 < kk; j += 2) {
        la = fmaf(tvv[j], gp[j], la);
        lb2 = fmaf(tvv[j + 1], gp[j + 1], lb2);
      }
      if (kk & 1) la = fmaf(tvv[kk - 1], gp[kk - 1], la);
      float lin = la + lb2;
      float e = __expf(2.f * lin);
      float tk = 1.f - 2.f / (e + 1.f);
      tvv[kk] = tk;
      float val = fabsf(fmaf(1.f - tk * tk, lds[OFF_C + kk], 1.f)) + 1e-8f;
      out[(size_t)B_ * D_ + (size_t)kk * B_ + row0 + t] = __logf(val);
    }
    // T -> LDS as bf16 hi/lo, layout [r][40]
#pragma unroll
    for (int q = 0; q < 4; ++q) {
      short8 th, tl;
#pragma unroll
      for (int i = 0; i < 8; ++i) {
        unsigned short hh, ll;
        bfsplit(tvv[q * 8 + i], hh, ll);
        th[i] = (short)hh;
        tl[i] = (short)ll;
      }
      *(short8*)&ldsH[XH_H + t * 40 + q * 8] = th;
      *(short8*)&ldsH[XL_H + t * 40 + q * 8] = tl;
    }
  }
  __syncthreads();

  // ---------------- stage Uhat^T hi/lo over dead W+P region ----------------
  {
    const uint4* usrc = (const uint4*)((const char*)ws + WSB_UTH);  // 40960 B
    uint4* udst = (uint4*)lds;
#pragma unroll
    for (int i = 0; i < 10; ++i) udst[t + 256 * i] = usrc[t + 256 * i];
  }
  __syncthreads();

  // ---------------- phase 3: Z = X + T . Uhat (MFMA, X via C operand) -------
  short8 tah[2], tal[2];
#pragma unroll
  for (int m = 0; m < 2; ++m) {
    const int hidx = XH_H + ((wv * 2 + m) * 16 + ln15) * 40 + g8;
    tah[m] = *(const short8*)&ldsH[hidx];
    tal[m] = *(const short8*)&ldsH[hidx + (XL_H - XH_H)];
  }
  for (int Nt = 0; Nt < 16; ++Nt) {
    const int uidx = (Nt * 16 + ln15) * 40 + g8;
    short8 bh = *(const short8*)&ldsH[UH_H + uidx];
    short8 bl = *(const short8*)&ldsH[UL_H + uidx];
    const int col = Nt * 16 + ln15;
#pragma unroll
    for (int m = 0; m < 2; ++m) {
      const size_t rbase = (size_t)row0 + (wv * 2 + m) * 16 + g4;
      f32x4 c;
#pragma unroll
      for (int q = 0; q < 4; ++q) c[q] = X[(rbase + q) * 256 + col];
      c = __builtin_amdgcn_mfma_f32_16x16x32_bf16(tah[m], bh, c, 0, 0, 0);
      c = __builtin_amdgcn_mfma_f32_16x16x32_bf16(tah[m], bl, c, 0, 0, 0);
      c = __builtin_amdgcn_mfma_f32_16x16x32_bf16(tal[m], bh, c, 0, 0, 0);
#pragma unroll
      for (int q = 0; q < 4; ++q) out[(rbase + q) * 256 + col] = c[q];
    }
  }
}

extern "C" void kernel_launch(void* const* d_in, const int* in_sizes, int n_in,
                              void* d_out, int out_size, void* d_ws, size_t ws_size,
                              hipStream_t stream) {
  const float* X = (const float*)d_in[0];
  // d_in[1] = h : unused by the math
  const float* u = (const float*)d_in[2];
  const float* w = (const float*)d_in[3];
  const float* b = (const float*)d_in[4];
  float* out = (float*)d_out;
  float* ws = (float*)d_ws;

  nf_gen<<<1, 256, 0, stream>>>(u, w, ws);
  nf_fused<<<GRID, 256, 0, stream>>>(X, b, ws, out);
}